// Round 2
// baseline (497.986 us; speedup 1.0000x reference)
//
#include <hip/hip_runtime.h>
#include <stdint.h>

#define BATCH 4
#define SEQ   2048
#define CH    1024
#define NH    16
#define HD    64

typedef __attribute__((ext_vector_type(8))) short bf16x8;
typedef __attribute__((ext_vector_type(4))) float f32x4;

__device__ inline unsigned short f2bf(float f) {
    unsigned u = __float_as_uint(f);
    u += 0x7fff + ((u >> 16) & 1);   // RNE
    return (unsigned short)(u >> 16);
}

__device__ inline void gld_lds16(const void* g, void* l) {
    __builtin_amdgcn_global_load_lds((const __attribute__((address_space(1))) void*)g,
                                     (__attribute__((address_space(3))) void*)l,
                                     16, 0, 0);
}

// ---------------- fp32 -> bf16 convert (vectorized) ----------------
__global__ __launch_bounds__(256) void cvt_bf16_k(const float* __restrict__ in,
                                                  unsigned short* __restrict__ out, int n) {
    int i = (blockIdx.x * 256 + threadIdx.x) * 8;
    if (i >= n) return;
    f32x4 a = *(const f32x4*)(in + i);
    f32x4 b = *(const f32x4*)(in + i + 4);
    union { bf16x8 v; unsigned short s[8]; } o;
    o.s[0] = f2bf(a[0]); o.s[1] = f2bf(a[1]); o.s[2] = f2bf(a[2]); o.s[3] = f2bf(a[3]);
    o.s[4] = f2bf(b[0]); o.s[5] = f2bf(b[1]); o.s[6] = f2bf(b[2]); o.s[7] = f2bf(b[3]);
    *(bf16x8*)(out + i) = o.v;
}

// ---------------- W (K x N fp32) -> W^T (N x K bf16) ----------------
__global__ __launch_bounds__(256) void transpose_w_k(const float* __restrict__ W,
                                                     unsigned short* __restrict__ Wt) {
    __shared__ float tile[32][33];
    const int bx = blockIdx.x * 32;   // n block
    const int by = blockIdx.y * 32;   // k block
    const int tx = threadIdx.x & 31;
    const int ty = threadIdx.x >> 5;  // 0..7
#pragma unroll
    for (int i = 0; i < 32; i += 8)
        tile[ty + i][tx] = W[(size_t)(by + ty + i) * CH + bx + tx];
    __syncthreads();
#pragma unroll
    for (int i = 0; i < 32; i += 8)
        Wt[(size_t)(bx + ty + i) * CH + by + tx] = f2bf(tile[tx][ty + i]);
}

// ---------------- GEMM: A(MxK bf16) @ Bt(NxK bf16)^T + bias ----------------
// MODE 0: out bf16, layout (B,H,T,64)   [Q/K projections]
// MODE 1: out bf16, layout (B,H,64,T)   [V projection, transposed]
// MODE 2: out fp32, row-major MxN       [final output projection]
template <int MODE>
__global__ __launch_bounds__(256, 2)
void gemm_bt(const unsigned short* __restrict__ A,
             const unsigned short* __restrict__ Bt,
             const float* __restrict__ bias,
             void* __restrict__ outp,
             int M, int N, int K) {
    __shared__ unsigned short As[128 * 64];
    __shared__ unsigned short Bs[128 * 64];
    const int tid  = threadIdx.x;
    const int lane = tid & 63;
    const int w    = tid >> 6;
    const int nbn  = N >> 7;
    const int m0   = (blockIdx.x / nbn) << 7;
    const int n0   = (blockIdx.x % nbn) << 7;
    const int wrow = (w >> 1) << 6;
    const int wcol = (w & 1) << 6;
    const int lr   = lane & 15;
    const int lg   = lane >> 4;

    f32x4 acc[4][4] = {};

    for (int k0 = 0; k0 < K; k0 += 64) {
#pragma unroll
        for (int i = 0; i < 4; ++i) {
            int chunk = i * 256 + tid;
            int row = chunk >> 3;
            int c8  = (chunk & 7) << 3;
            gld_lds16(A  + (size_t)(m0 + row) * K + k0 + c8, (char*)As + chunk * 16);
            gld_lds16(Bt + (size_t)(n0 + row) * K + k0 + c8, (char*)Bs + chunk * 16);
        }
        __syncthreads();
#pragma unroll
        for (int kk = 0; kk < 2; ++kk) {
            bf16x8 af[4], bfr[4];
#pragma unroll
            for (int f = 0; f < 4; ++f)
                af[f] = *(const bf16x8*)(As + (wrow + f * 16 + lr) * 64 + kk * 32 + lg * 8);
#pragma unroll
            for (int f = 0; f < 4; ++f)
                bfr[f] = *(const bf16x8*)(Bs + (wcol + f * 16 + lr) * 64 + kk * 32 + lg * 8);
#pragma unroll
            for (int i = 0; i < 4; ++i)
#pragma unroll
                for (int j = 0; j < 4; ++j)
                    acc[i][j] = __builtin_amdgcn_mfma_f32_16x16x32_bf16(af[i], bfr[j], acc[i][j], 0, 0, 0);
        }
        __syncthreads();
    }

    float bvals[4];
#pragma unroll
    for (int j = 0; j < 4; ++j) bvals[j] = bias[n0 + wcol + j * 16 + lr];

#pragma unroll
    for (int i = 0; i < 4; ++i) {
        const int mbase = m0 + wrow + i * 16 + lg * 4;
#pragma unroll
        for (int j = 0; j < 4; ++j) {
            const int n = n0 + wcol + j * 16 + lr;
            if (MODE == 2) {
                float* out = (float*)outp;
#pragma unroll
                for (int r = 0; r < 4; ++r)
                    out[(size_t)(mbase + r) * N + n] = acc[i][j][r] + bvals[j];
            } else if (MODE == 0) {
                unsigned short* out = (unsigned short*)outp;
                const int h = n >> 6, d = n & 63;
#pragma unroll
                for (int r = 0; r < 4; ++r) {
                    const int m = mbase + r;
                    const int b = m >> 11, t = m & 2047;
                    out[((size_t)(b * NH + h) * SEQ + t) * HD + d] = f2bf(acc[i][j][r] + bvals[j]);
                }
            } else { // MODE 1: (B,H,D,T), pack 4 consecutive t
                unsigned short* out = (unsigned short*)outp;
                const int h = n >> 6, d = n & 63;
                const int b = mbase >> 11, t = mbase & 2047;
                union { unsigned short s[4]; uint2 v; } pk;
#pragma unroll
                for (int r = 0; r < 4; ++r) pk.s[r] = f2bf(acc[i][j][r] + bvals[j]);
                *(uint2*)(out + ((size_t)(b * NH + h) * HD + d) * SEQ + t) = pk.v;
            }
        }
    }
}

// ---------------- flash attention ----------------
// Grid (SEQ/128, B*H). 4 waves; wave w owns q rows [q0+32w, q0+32w+32).
// K/V double-buffered in LDS with XOR-swizzled layout (swizzle applied on the
// *global source address* of global_load_lds — LDS dest stays linear — and on
// every ds_read offset; same involution both sides, rule #21).
__global__ __launch_bounds__(256, 3)
void attn_k(const unsigned short* __restrict__ Qh,   // (BH, T, 64)
            const unsigned short* __restrict__ Kh,   // (BH, T, 64)
            const unsigned short* __restrict__ Vt,   // (BH, 64, T)
            unsigned short* __restrict__ O) {        // (B, T, H*64)
    __shared__ unsigned short Ks[2][64 * 64];
    __shared__ unsigned short Vs[2][64 * 64];   // [d][kv]
    __shared__ unsigned short Ps[4][32 * 64];   // per-wave P tile (swizzled)
    const int qtile = (gridDim.x - 1) - blockIdx.x;   // longest blocks first
    const int bh   = blockIdx.y;
    const int q0   = qtile << 7;
    const int tid  = threadIdx.x;
    const int lane = tid & 63;
    const int w    = tid >> 6;
    const int lr   = lane & 15;
    const int lg   = lane >> 4;
    const int qw   = q0 + w * 32;          // wave's first q row
    unsigned short* Pw = Ps[w];
    const int swz = (lr & 7) << 3;         // element-offset XOR for row=...+lr reads

    // Q fragments in registers (rows qw+qi*16+lr, d = kk*32+lg*8)
    bf16x8 qf[2][2];
#pragma unroll
    for (int qi = 0; qi < 2; ++qi)
#pragma unroll
        for (int kk = 0; kk < 2; ++kk)
            qf[qi][kk] = *(const bf16x8*)(Qh + ((size_t)bh * SEQ + qw + qi * 16 + lr) * HD + kk * 32 + lg * 8);

    float mrun[2][4], lrun[2][4];
    f32x4 oacc[2][4] = {};
#pragma unroll
    for (int qi = 0; qi < 2; ++qi)
#pragma unroll
        for (int r = 0; r < 4; ++r) { mrun[qi][r] = -3e38f; lrun[qi][r] = 0.f; }

    const int nkt = 2 * qtile + 2;   // kv tiles of 64 covering [0, q0+128)

    // stage tile kt into buffer b (K rows=kv, V rows=d; source pre-swizzled)
#define STAGE(KT, B) do {                                                          \
        const int kv_ = (KT) << 6;                                                 \
        _Pragma("unroll")                                                          \
        for (int i_ = 0; i_ < 2; ++i_) {                                           \
            int c_ = i_ * 256 + tid;                                               \
            int row_ = c_ >> 3;                                                    \
            int so_ = (((c_ & 7) ^ (row_ & 7)) << 3);                              \
            gld_lds16(Kh + ((size_t)bh * SEQ + kv_ + row_) * HD + so_,             \
                      (char*)Ks[B] + c_ * 16);                                     \
            gld_lds16(Vt + ((size_t)bh * HD + row_) * SEQ + kv_ + so_,             \
                      (char*)Vs[B] + c_ * 16);                                     \
        }                                                                          \
    } while (0)

    STAGE(0, 0);
    __syncthreads();

    for (int kt = 0; kt < nkt; ++kt) {
        if (kt + 1 < nkt) STAGE(kt + 1, (kt + 1) & 1);
        const unsigned short* Kc = Ks[kt & 1];
        const unsigned short* Vc = Vs[kt & 1];
        const int kv0 = kt << 6;

        if (kv0 <= qw + 31) {   // wave has at least one unmasked row
            // ---- QK^T ----
            f32x4 s[2][4] = {};
#pragma unroll
            for (int kk = 0; kk < 2; ++kk) {
                const int u = (((kk << 2) | lg) ^ (lr & 7)) << 3;
#pragma unroll
                for (int f = 0; f < 4; ++f) {
                    bf16x8 kb = *(const bf16x8*)(Kc + (f * 16 + lr) * 64 + u);
                    s[0][f] = __builtin_amdgcn_mfma_f32_16x16x32_bf16(qf[0][kk], kb, s[0][f], 0, 0, 0);
                    s[1][f] = __builtin_amdgcn_mfma_f32_16x16x32_bf16(qf[1][kk], kb, s[1][f], 0, 0, 0);
                }
            }

            // ---- scale + causal mask + row max ----
            const bool full = (kv0 + 63 <= qw);   // no masking needed for whole wave
            float rmax[2][4];
#pragma unroll
            for (int qi = 0; qi < 2; ++qi)
#pragma unroll
                for (int r = 0; r < 4; ++r) rmax[qi][r] = -3e38f;
#pragma unroll
            for (int qi = 0; qi < 2; ++qi)
#pragma unroll
                for (int f = 0; f < 4; ++f)
#pragma unroll
                    for (int r = 0; r < 4; ++r) {
                        float v = s[qi][f][r] * 0.125f;
                        if (!full) {
                            const int q  = qw + qi * 16 + lg * 4 + r;
                            const int kv = kv0 + f * 16 + lr;
                            if (kv > q) v = -3e38f;
                        }
                        s[qi][f][r] = v;
                        rmax[qi][r] = fmaxf(rmax[qi][r], v);
                    }
#pragma unroll
            for (int d = 1; d < 16; d <<= 1)
#pragma unroll
                for (int qi = 0; qi < 2; ++qi)
#pragma unroll
                    for (int r = 0; r < 4; ++r)
                        rmax[qi][r] = fmaxf(rmax[qi][r], __shfl_xor(rmax[qi][r], d));

            // ---- online softmax ----
            float corr[2][4], psum[2][4];
#pragma unroll
            for (int qi = 0; qi < 2; ++qi)
#pragma unroll
                for (int r = 0; r < 4; ++r) {
                    float mn = fmaxf(mrun[qi][r], rmax[qi][r]);
                    corr[qi][r] = __expf(mrun[qi][r] - mn);
                    mrun[qi][r] = mn;
                    psum[qi][r] = 0.f;
                }
#pragma unroll
            for (int qi = 0; qi < 2; ++qi)
#pragma unroll
                for (int f = 0; f < 4; ++f)
#pragma unroll
                    for (int r = 0; r < 4; ++r) {
                        float pv = __expf(s[qi][f][r] - mrun[qi][r]);
                        s[qi][f][r] = pv;
                        psum[qi][r] += pv;
                    }
#pragma unroll
            for (int d = 1; d < 16; d <<= 1)
#pragma unroll
                for (int qi = 0; qi < 2; ++qi)
#pragma unroll
                    for (int r = 0; r < 4; ++r)
                        psum[qi][r] += __shfl_xor(psum[qi][r], d);
#pragma unroll
            for (int qi = 0; qi < 2; ++qi)
#pragma unroll
                for (int r = 0; r < 4; ++r)
                    lrun[qi][r] = lrun[qi][r] * corr[qi][r] + psum[qi][r];
#pragma unroll
            for (int qi = 0; qi < 2; ++qi)
#pragma unroll
                for (int f = 0; f < 4; ++f)
#pragma unroll
                    for (int r = 0; r < 4; ++r) oacc[qi][f][r] *= corr[qi][r];

            // ---- P -> LDS (swizzled), reload as A-fragments ----
#pragma unroll
            for (int qi = 0; qi < 2; ++qi)
#pragma unroll
                for (int f = 0; f < 4; ++f)
#pragma unroll
                    for (int r = 0; r < 4; ++r) {
                        const int prow = qi * 16 + lg * 4 + r;
                        Pw[prow * 64 + ((f * 16 + lr) ^ ((prow & 7) << 3))] = f2bf(s[qi][f][r]);
                    }

            bf16x8 pa[2][2];
#pragma unroll
            for (int qi = 0; qi < 2; ++qi)
#pragma unroll
                for (int kk = 0; kk < 2; ++kk)
                    pa[qi][kk] = *(const bf16x8*)(Pw + (qi * 16 + lr) * 64 + ((((kk << 2) | lg) ^ (lr & 7)) << 3));

            // ---- PV ----
#pragma unroll
            for (int kk = 0; kk < 2; ++kk) {
                const int u = (((kk << 2) | lg) ^ (lr & 7)) << 3;
#pragma unroll
                for (int f = 0; f < 4; ++f) {
                    bf16x8 vb = *(const bf16x8*)(Vc + (f * 16 + lr) * 64 + u);
                    oacc[0][f] = __builtin_amdgcn_mfma_f32_16x16x32_bf16(pa[0][kk], vb, oacc[0][f], 0, 0, 0);
                    oacc[1][f] = __builtin_amdgcn_mfma_f32_16x16x32_bf16(pa[1][kk], vb, oacc[1][f], 0, 0, 0);
                }
            }
        }
        __syncthreads();
    }
#undef STAGE

    const int b = bh >> 4, h = bh & 15;
    float inv[2][4];
#pragma unroll
    for (int qi = 0; qi < 2; ++qi)
#pragma unroll
        for (int r = 0; r < 4; ++r) inv[qi][r] = 1.0f / lrun[qi][r];
#pragma unroll
    for (int qi = 0; qi < 2; ++qi)
#pragma unroll
        for (int f = 0; f < 4; ++f) {
            const int d = f * 16 + lr;
#pragma unroll
            for (int r = 0; r < 4; ++r) {
                const int t = qw + qi * 16 + lg * 4 + r;
                O[((size_t)b * SEQ + t) * CH + h * HD + d] = f2bf(oacc[qi][f][r] * inv[qi][r]);
            }
        }
}

extern "C" void kernel_launch(void* const* d_in, const int* in_sizes, int n_in,
                              void* d_out, int out_size, void* d_ws, size_t ws_size,
                              hipStream_t stream) {
    const float* Q  = (const float*)d_in[0];
    const float* K  = (const float*)d_in[1];
    const float* V  = (const float*)d_in[2];
    // d_in[3] = mask: always causal triu(k=1); applied analytically in attn_k
    const float* Wq = (const float*)d_in[4];
    const float* bq = (const float*)d_in[5];
    const float* Wk = (const float*)d_in[6];
    const float* bk = (const float*)d_in[7];
    const float* Wv = (const float*)d_in[8];
    const float* bv = (const float*)d_in[9];
    const float* Wo = (const float*)d_in[10];
    const float* bo = (const float*)d_in[11];
    float* out = (float*)d_out;

    const size_t SZ_ACT = (size_t)BATCH * SEQ * CH;  // 8388608
    const size_t SZ_W   = (size_t)CH * CH;           // 1048576

    char* p = (char*)d_ws;
    unsigned short* Qbf = (unsigned short*)p; p += SZ_ACT * 2;
    unsigned short* Kbf = (unsigned short*)p; p += SZ_ACT * 2;
    unsigned short* Vbf = (unsigned short*)p; p += SZ_ACT * 2;
    unsigned short* WqT = (unsigned short*)p; p += SZ_W * 2;
    unsigned short* WkT = (unsigned short*)p; p += SZ_W * 2;
    unsigned short* WvT = (unsigned short*)p; p += SZ_W * 2;
    unsigned short* WoT = (unsigned short*)p; p += SZ_W * 2;
    unsigned short* Qhb = (unsigned short*)p; p += SZ_ACT * 2;
    unsigned short* Khb = (unsigned short*)p; p += SZ_ACT * 2;
    unsigned short* Vtb = (unsigned short*)p; p += SZ_ACT * 2;
    unsigned short* Ob  = Qbf;  // Qbf is dead after the Q projection; reuse for attn output

    const int nconv = (int)SZ_ACT;
    const int cblocks = (int)(SZ_ACT / (256 * 8));
    cvt_bf16_k<<<cblocks, 256, 0, stream>>>(Q, Qbf, nconv);
    cvt_bf16_k<<<cblocks, 256, 0, stream>>>(K, Kbf, nconv);
    cvt_bf16_k<<<cblocks, 256, 0, stream>>>(V, Vbf, nconv);

    transpose_w_k<<<dim3(32, 32), 256, 0, stream>>>(Wq, WqT);
    transpose_w_k<<<dim3(32, 32), 256, 0, stream>>>(Wk, WkT);
    transpose_w_k<<<dim3(32, 32), 256, 0, stream>>>(Wv, WvT);
    transpose_w_k<<<dim3(32, 32), 256, 0, stream>>>(Wo, WoT);

    const int M = BATCH * SEQ;  // 8192
    gemm_bt<0><<<(M / 128) * (CH / 128), 256, 0, stream>>>(Qbf, WqT, bq, Qhb, M, CH, CH);
    gemm_bt<0><<<(M / 128) * (CH / 128), 256, 0, stream>>>(Kbf, WkT, bk, Khb, M, CH, CH);
    gemm_bt<1><<<(M / 128) * (CH / 128), 256, 0, stream>>>(Vbf, WvT, bv, Vtb, M, CH, CH);

    attn_k<<<dim3(SEQ / 128, BATCH * NH), 256, 0, stream>>>(Qhb, Khb, Vtb, Ob);

    gemm_bt<2><<<(M / 128) * (CH / 128), 256, 0, stream>>>(Ob, WoT, bo, out, M, CH, CH);
}

// Round 3
// 260.992 us; speedup vs baseline: 1.9080x; 1.9080x over previous
//
#include <hip/hip_runtime.h>
#include <stdint.h>

#define BATCH 4
#define SEQ   2048
#define CH    1024
#define NH    16
#define HD    64

typedef __attribute__((ext_vector_type(8))) short bf16x8;
typedef __attribute__((ext_vector_type(4))) float f32x4;

__device__ inline unsigned short f2bf(float f) {
    unsigned u = __float_as_uint(f);
    u += 0x7fff + ((u >> 16) & 1);   // RNE
    return (unsigned short)(u >> 16);
}

__device__ inline void gld_lds16(const void* g, void* l) {
    __builtin_amdgcn_global_load_lds((const __attribute__((address_space(1))) void*)g,
                                     (__attribute__((address_space(3))) void*)l,
                                     16, 0, 0);
}

// ---------------- fp32 -> bf16 convert (vectorized) ----------------
__global__ __launch_bounds__(256) void cvt_bf16_k(const float* __restrict__ in,
                                                  unsigned short* __restrict__ out, int n) {
    int i = (blockIdx.x * 256 + threadIdx.x) * 8;
    if (i >= n) return;
    f32x4 a = *(const f32x4*)(in + i);
    f32x4 b = *(const f32x4*)(in + i + 4);
    union { bf16x8 v; unsigned short s[8]; } o;
    o.s[0] = f2bf(a[0]); o.s[1] = f2bf(a[1]); o.s[2] = f2bf(a[2]); o.s[3] = f2bf(a[3]);
    o.s[4] = f2bf(b[0]); o.s[5] = f2bf(b[1]); o.s[6] = f2bf(b[2]); o.s[7] = f2bf(b[3]);
    *(bf16x8*)(out + i) = o.v;
}

// ---------------- W (K x N fp32) -> W^T (N x K bf16) ----------------
__global__ __launch_bounds__(256) void transpose_w_k(const float* __restrict__ W,
                                                     unsigned short* __restrict__ Wt) {
    __shared__ float tile[32][33];
    const int bx = blockIdx.x * 32;   // n block
    const int by = blockIdx.y * 32;   // k block
    const int tx = threadIdx.x & 31;
    const int ty = threadIdx.x >> 5;  // 0..7
#pragma unroll
    for (int i = 0; i < 32; i += 8)
        tile[ty + i][tx] = W[(size_t)(by + ty + i) * CH + bx + tx];
    __syncthreads();
#pragma unroll
    for (int i = 0; i < 32; i += 8)
        Wt[(size_t)(bx + ty + i) * CH + by + tx] = f2bf(tile[tx][ty + i]);
}

// ---------------- GEMM: A(MxK bf16) @ Bt(NxK bf16)^T + bias ----------------
// MODE 0: out bf16, layout (B,H,T,64)   [Q/K projections]
// MODE 1: out bf16, layout (B,H,64,T)   [V projection, transposed]
// MODE 2: out fp32, row-major MxN       [final output projection]
template <int MODE>
__global__ __launch_bounds__(256, 2)
void gemm_bt(const unsigned short* __restrict__ A,
             const unsigned short* __restrict__ Bt,
             const float* __restrict__ bias,
             void* __restrict__ outp,
             int M, int N, int K) {
    __shared__ unsigned short As[128 * 64];
    __shared__ unsigned short Bs[128 * 64];
    const int tid  = threadIdx.x;
    const int lane = tid & 63;
    const int w    = tid >> 6;
    const int nbn  = N >> 7;
    const int m0   = (blockIdx.x / nbn) << 7;
    const int n0   = (blockIdx.x % nbn) << 7;
    const int wrow = (w >> 1) << 6;
    const int wcol = (w & 1) << 6;
    const int lr   = lane & 15;
    const int lg   = lane >> 4;

    f32x4 acc[4][4] = {};

    for (int k0 = 0; k0 < K; k0 += 64) {
#pragma unroll
        for (int i = 0; i < 4; ++i) {
            int chunk = i * 256 + tid;
            int row = chunk >> 3;
            int c8  = (chunk & 7) << 3;
            gld_lds16(A  + (size_t)(m0 + row) * K + k0 + c8, (char*)As + chunk * 16);
            gld_lds16(Bt + (size_t)(n0 + row) * K + k0 + c8, (char*)Bs + chunk * 16);
        }
        __syncthreads();
#pragma unroll
        for (int kk = 0; kk < 2; ++kk) {
            bf16x8 af[4], bfr[4];
#pragma unroll
            for (int f = 0; f < 4; ++f)
                af[f] = *(const bf16x8*)(As + (wrow + f * 16 + lr) * 64 + kk * 32 + lg * 8);
#pragma unroll
            for (int f = 0; f < 4; ++f)
                bfr[f] = *(const bf16x8*)(Bs + (wcol + f * 16 + lr) * 64 + kk * 32 + lg * 8);
#pragma unroll
            for (int i = 0; i < 4; ++i)
#pragma unroll
                for (int j = 0; j < 4; ++j)
                    acc[i][j] = __builtin_amdgcn_mfma_f32_16x16x32_bf16(af[i], bfr[j], acc[i][j], 0, 0, 0);
        }
        __syncthreads();
    }

    float bvals[4];
#pragma unroll
    for (int j = 0; j < 4; ++j) bvals[j] = bias[n0 + wcol + j * 16 + lr];

#pragma unroll
    for (int i = 0; i < 4; ++i) {
        const int mbase = m0 + wrow + i * 16 + lg * 4;
#pragma unroll
        for (int j = 0; j < 4; ++j) {
            const int n = n0 + wcol + j * 16 + lr;
            if (MODE == 2) {
                float* out = (float*)outp;
#pragma unroll
                for (int r = 0; r < 4; ++r)
                    out[(size_t)(mbase + r) * N + n] = acc[i][j][r] + bvals[j];
            } else if (MODE == 0) {
                unsigned short* out = (unsigned short*)outp;
                const int h = n >> 6, d = n & 63;
#pragma unroll
                for (int r = 0; r < 4; ++r) {
                    const int m = mbase + r;
                    const int b = m >> 11, t = m & 2047;
                    out[((size_t)(b * NH + h) * SEQ + t) * HD + d] = f2bf(acc[i][j][r] + bvals[j]);
                }
            } else { // MODE 1: (B,H,D,T), pack 4 consecutive t
                unsigned short* out = (unsigned short*)outp;
                const int h = n >> 6, d = n & 63;
                const int b = mbase >> 11, t = mbase & 2047;
                union { unsigned short s[4]; uint2 v; } pk;
#pragma unroll
                for (int r = 0; r < 4; ++r) pk.s[r] = f2bf(acc[i][j][r] + bvals[j]);
                *(uint2*)(out + ((size_t)(b * NH + h) * HD + d) * SEQ + t) = pk.v;
            }
        }
    }
}

// ---------------- flash attention ----------------
// Grid (bh=64, qtile=32), qtile = 31 - blockIdx.y so ALL longest blocks
// dispatch first (minimal tail). 4 waves; wave w owns q rows
// [q0+16w, q0+16w+16). K/V double-buffered + XOR-swizzled (swizzle on the
// global source of global_load_lds, LDS linear; same XOR on ds_read).
// One barrier per kv tile.
__global__ __launch_bounds__(256, 4)
void attn_k(const unsigned short* __restrict__ Qh,   // (BH, T, 64)
            const unsigned short* __restrict__ Kh,   // (BH, T, 64)
            const unsigned short* __restrict__ Vt,   // (BH, 64, T)
            unsigned short* __restrict__ O) {        // (B, T, H*64)
    __shared__ unsigned short Ks[2][64 * 64];
    __shared__ unsigned short Vs[2][64 * 64];   // [d][kv]
    __shared__ unsigned short Ps[4][16 * 64];   // per-wave P tile (swizzled)
    const int bh    = blockIdx.x;
    const int qtile = 31 - blockIdx.y;          // longest first
    const int q0    = qtile << 6;
    const int tid  = threadIdx.x;
    const int lane = tid & 63;
    const int w    = tid >> 6;
    const int lr   = lane & 15;
    const int lg   = lane >> 4;
    const int qw   = q0 + w * 16;               // wave's first q row
    unsigned short* Pw = Ps[w];

    // Q fragment in registers (rows qw+lr, d = kk*32+lg*8)
    bf16x8 qf[2];
#pragma unroll
    for (int kk = 0; kk < 2; ++kk)
        qf[kk] = *(const bf16x8*)(Qh + ((size_t)bh * SEQ + qw + lr) * HD + kk * 32 + lg * 8);

    float mrun[4], lrun[4];
    f32x4 oacc[4] = {};
#pragma unroll
    for (int r = 0; r < 4; ++r) { mrun[r] = -3e38f; lrun[r] = 0.f; }

    const int nkt = qtile + 1;   // kv tiles of 64 covering [0, q0+64)

#define STAGE(KT, B) do {                                                          \
        const int kv_ = (KT) << 6;                                                 \
        _Pragma("unroll")                                                          \
        for (int i_ = 0; i_ < 2; ++i_) {                                           \
            int c_ = i_ * 256 + tid;                                               \
            int row_ = c_ >> 3;                                                    \
            int so_ = (((c_ & 7) ^ (row_ & 7)) << 3);                              \
            gld_lds16(Kh + ((size_t)bh * SEQ + kv_ + row_) * HD + so_,             \
                      (char*)Ks[B] + c_ * 16);                                     \
            gld_lds16(Vt + ((size_t)bh * HD + row_) * SEQ + kv_ + so_,             \
                      (char*)Vs[B] + c_ * 16);                                     \
        }                                                                          \
    } while (0)

    STAGE(0, 0);
    __syncthreads();

    for (int kt = 0; kt < nkt; ++kt) {
        if (kt + 1 < nkt) STAGE(kt + 1, (kt + 1) & 1);
        const unsigned short* Kc = Ks[kt & 1];
        const unsigned short* Vc = Vs[kt & 1];
        const int kv0 = kt << 6;

        if (kv0 <= qw + 15) {   // wave has at least one unmasked row
            // ---- QK^T ----
            f32x4 s[4] = {};
#pragma unroll
            for (int kk = 0; kk < 2; ++kk) {
                const int u = (((kk << 2) | lg) ^ (lr & 7)) << 3;
#pragma unroll
                for (int f = 0; f < 4; ++f) {
                    bf16x8 kb = *(const bf16x8*)(Kc + (f * 16 + lr) * 64 + u);
                    s[f] = __builtin_amdgcn_mfma_f32_16x16x32_bf16(qf[kk], kb, s[f], 0, 0, 0);
                }
            }

            // ---- scale + causal mask + row max ----
            const bool full = (kv0 + 63 <= qw);
            float rmax[4];
#pragma unroll
            for (int r = 0; r < 4; ++r) rmax[r] = -3e38f;
#pragma unroll
            for (int f = 0; f < 4; ++f)
#pragma unroll
                for (int r = 0; r < 4; ++r) {
                    float v = s[f][r] * 0.125f;
                    if (!full) {
                        const int q  = qw + lg * 4 + r;
                        const int kv = kv0 + f * 16 + lr;
                        if (kv > q) v = -3e38f;
                    }
                    s[f][r] = v;
                    rmax[r] = fmaxf(rmax[r], v);
                }
#pragma unroll
            for (int d = 1; d < 16; d <<= 1)
#pragma unroll
                for (int r = 0; r < 4; ++r)
                    rmax[r] = fmaxf(rmax[r], __shfl_xor(rmax[r], d));

            // ---- online softmax ----
            float corr[4], psum[4];
#pragma unroll
            for (int r = 0; r < 4; ++r) {
                float mn = fmaxf(mrun[r], rmax[r]);
                corr[r] = __expf(mrun[r] - mn);
                mrun[r] = mn;
                psum[r] = 0.f;
            }
#pragma unroll
            for (int f = 0; f < 4; ++f)
#pragma unroll
                for (int r = 0; r < 4; ++r) {
                    float pv = __expf(s[f][r] - mrun[r]);
                    s[f][r] = pv;
                    psum[r] += pv;
                }
#pragma unroll
            for (int d = 1; d < 16; d <<= 1)
#pragma unroll
                for (int r = 0; r < 4; ++r)
                    psum[r] += __shfl_xor(psum[r], d);
#pragma unroll
            for (int r = 0; r < 4; ++r)
                lrun[r] = lrun[r] * corr[r] + psum[r];
#pragma unroll
            for (int f = 0; f < 4; ++f)
#pragma unroll
                for (int r = 0; r < 4; ++r) oacc[f][r] *= corr[r];

            // ---- P -> per-wave LDS (swizzled), reload as A-fragments ----
#pragma unroll
            for (int f = 0; f < 4; ++f)
#pragma unroll
                for (int r = 0; r < 4; ++r) {
                    const int prow = lg * 4 + r;
                    Pw[prow * 64 + ((f * 16 + lr) ^ ((prow & 7) << 3))] = f2bf(s[f][r]);
                }

            bf16x8 pa[2];
#pragma unroll
            for (int kk = 0; kk < 2; ++kk)
                pa[kk] = *(const bf16x8*)(Pw + lr * 64 + ((((kk << 2) | lg) ^ (lr & 7)) << 3));

            // ---- PV ----
#pragma unroll
            for (int kk = 0; kk < 2; ++kk) {
                const int u = (((kk << 2) | lg) ^ (lr & 7)) << 3;
#pragma unroll
                for (int f = 0; f < 4; ++f) {
                    bf16x8 vb = *(const bf16x8*)(Vc + (f * 16 + lr) * 64 + u);
                    oacc[f] = __builtin_amdgcn_mfma_f32_16x16x32_bf16(pa[kk], vb, oacc[f], 0, 0, 0);
                }
            }
        }
        __syncthreads();
    }
#undef STAGE

    const int b = bh >> 4, h = bh & 15;
    float inv[4];
#pragma unroll
    for (int r = 0; r < 4; ++r) inv[r] = 1.0f / lrun[r];
#pragma unroll
    for (int f = 0; f < 4; ++f) {
        const int d = f * 16 + lr;
#pragma unroll
        for (int r = 0; r < 4; ++r) {
            const int t = qw + lg * 4 + r;
            O[((size_t)b * SEQ + t) * CH + h * HD + d] = f2bf(oacc[f][r] * inv[r]);
        }
    }
}

extern "C" void kernel_launch(void* const* d_in, const int* in_sizes, int n_in,
                              void* d_out, int out_size, void* d_ws, size_t ws_size,
                              hipStream_t stream) {
    const float* Q  = (const float*)d_in[0];
    const float* K  = (const float*)d_in[1];
    const float* V  = (const float*)d_in[2];
    // d_in[3] = mask: always causal triu(k=1); applied analytically in attn_k
    const float* Wq = (const float*)d_in[4];
    const float* bq = (const float*)d_in[5];
    const float* Wk = (const float*)d_in[6];
    const float* bk = (const float*)d_in[7];
    const float* Wv = (const float*)d_in[8];
    const float* bv = (const float*)d_in[9];
    const float* Wo = (const float*)d_in[10];
    const float* bo = (const float*)d_in[11];
    float* out = (float*)d_out;

    const size_t SZ_ACT = (size_t)BATCH * SEQ * CH;  // 8388608
    const size_t SZ_W   = (size_t)CH * CH;           // 1048576

    char* p = (char*)d_ws;
    unsigned short* Qbf = (unsigned short*)p; p += SZ_ACT * 2;
    unsigned short* Kbf = (unsigned short*)p; p += SZ_ACT * 2;
    unsigned short* Vbf = (unsigned short*)p; p += SZ_ACT * 2;
    unsigned short* WqT = (unsigned short*)p; p += SZ_W * 2;
    unsigned short* WkT = (unsigned short*)p; p += SZ_W * 2;
    unsigned short* WvT = (unsigned short*)p; p += SZ_W * 2;
    unsigned short* WoT = (unsigned short*)p; p += SZ_W * 2;
    unsigned short* Qhb = (unsigned short*)p; p += SZ_ACT * 2;
    unsigned short* Khb = (unsigned short*)p; p += SZ_ACT * 2;
    unsigned short* Vtb = (unsigned short*)p; p += SZ_ACT * 2;
    unsigned short* Ob  = Qbf;  // Qbf is dead after the Q projection; reuse for attn output

    const int nconv = (int)SZ_ACT;
    const int cblocks = (int)(SZ_ACT / (256 * 8));
    cvt_bf16_k<<<cblocks, 256, 0, stream>>>(Q, Qbf, nconv);
    cvt_bf16_k<<<cblocks, 256, 0, stream>>>(K, Kbf, nconv);
    cvt_bf16_k<<<cblocks, 256, 0, stream>>>(V, Vbf, nconv);

    transpose_w_k<<<dim3(32, 32), 256, 0, stream>>>(Wq, WqT);
    transpose_w_k<<<dim3(32, 32), 256, 0, stream>>>(Wk, WkT);
    transpose_w_k<<<dim3(32, 32), 256, 0, stream>>>(Wv, WvT);
    transpose_w_k<<<dim3(32, 32), 256, 0, stream>>>(Wo, WoT);

    const int M = BATCH * SEQ;  // 8192
    gemm_bt<0><<<(M / 128) * (CH / 128), 256, 0, stream>>>(Qbf, WqT, bq, Qhb, M, CH, CH);
    gemm_bt<0><<<(M / 128) * (CH / 128), 256, 0, stream>>>(Kbf, WkT, bk, Khb, M, CH, CH);
    gemm_bt<1><<<(M / 128) * (CH / 128), 256, 0, stream>>>(Vbf, WvT, bv, Vtb, M, CH, CH);

    attn_k<<<dim3(BATCH * NH, SEQ / 64), 256, 0, stream>>>(Qhb, Khb, Vtb, Ob);

    gemm_bt<2><<<(M / 128) * (CH / 128), 256, 0, stream>>>(Ob, WoT, bo, out, M, CH, CH);
}

// Round 4
// 239.481 us; speedup vs baseline: 2.0794x; 1.0898x over previous
//
#include <hip/hip_runtime.h>
#include <stdint.h>

#define BATCH 4
#define SEQ   2048
#define CH    1024
#define NH    16
#define HD    64

// 0.125 (1/sqrt(64)) * log2(e): folded into Q so softmax runs in log2 domain.
#define QSCALE 0.18033688011112042f

typedef __attribute__((ext_vector_type(8))) short bf16x8;
typedef __attribute__((ext_vector_type(4))) float f32x4;

__device__ inline unsigned short f2bf(float f) {
    unsigned u = __float_as_uint(f);
    u += 0x7fff + ((u >> 16) & 1);   // RNE
    return (unsigned short)(u >> 16);
}

__device__ inline float fast_exp2(float x) {
    float r;
    asm("v_exp_f32 %0, %1" : "=v"(r) : "v"(x));
    return r;
}

__device__ inline unsigned cvt_pk_bf16(float lo, float hi) {
    unsigned r;
    asm("v_cvt_pk_bf16_f32 %0, %1, %2" : "=v"(r) : "v"(lo), "v"(hi));
    return r;
}

__device__ inline void gld_lds16(const void* g, void* l) {
    __builtin_amdgcn_global_load_lds((const __attribute__((address_space(1))) void*)g,
                                     (__attribute__((address_space(3))) void*)l,
                                     16, 0, 0);
}

// ---------------- fp32 -> bf16 convert (vectorized) ----------------
__global__ __launch_bounds__(256) void cvt_bf16_k(const float* __restrict__ in,
                                                  unsigned short* __restrict__ out, int n) {
    int i = (blockIdx.x * 256 + threadIdx.x) * 8;
    if (i >= n) return;
    f32x4 a = *(const f32x4*)(in + i);
    f32x4 b = *(const f32x4*)(in + i + 4);
    union { bf16x8 v; unsigned short s[8]; } o;
    o.s[0] = f2bf(a[0]); o.s[1] = f2bf(a[1]); o.s[2] = f2bf(a[2]); o.s[3] = f2bf(a[3]);
    o.s[4] = f2bf(b[0]); o.s[5] = f2bf(b[1]); o.s[6] = f2bf(b[2]); o.s[7] = f2bf(b[3]);
    *(bf16x8*)(out + i) = o.v;
}

// ---------------- W (K x N fp32) -> W^T (N x K bf16) ----------------
__global__ __launch_bounds__(256) void transpose_w_k(const float* __restrict__ W,
                                                     unsigned short* __restrict__ Wt) {
    __shared__ float tile[32][33];
    const int bx = blockIdx.x * 32;   // n block
    const int by = blockIdx.y * 32;   // k block
    const int tx = threadIdx.x & 31;
    const int ty = threadIdx.x >> 5;  // 0..7
#pragma unroll
    for (int i = 0; i < 32; i += 8)
        tile[ty + i][tx] = W[(size_t)(by + ty + i) * CH + bx + tx];
    __syncthreads();
#pragma unroll
    for (int i = 0; i < 32; i += 8)
        Wt[(size_t)(bx + ty + i) * CH + by + tx] = f2bf(tile[tx][ty + i]);
}

// ---------------- GEMM: A(MxK bf16) @ Bt(NxK bf16)^T + bias ----------------
// MODE 0: out bf16 * oscale, layout (B,H,T,64)   [Q/K projections]
// MODE 1: out bf16, layout (B,H,64,T)            [V projection, transposed]
// MODE 2: out fp32, row-major MxN                [final output projection]
template <int MODE>
__global__ __launch_bounds__(256, 2)
void gemm_bt(const unsigned short* __restrict__ A,
             const unsigned short* __restrict__ Bt,
             const float* __restrict__ bias,
             void* __restrict__ outp,
             int M, int N, int K, float oscale) {
    __shared__ unsigned short As[128 * 64];
    __shared__ unsigned short Bs[128 * 64];
    const int tid  = threadIdx.x;
    const int lane = tid & 63;
    const int w    = tid >> 6;
    const int nbn  = N >> 7;
    const int m0   = (blockIdx.x / nbn) << 7;
    const int n0   = (blockIdx.x % nbn) << 7;
    const int wrow = (w >> 1) << 6;
    const int wcol = (w & 1) << 6;
    const int lr   = lane & 15;
    const int lg   = lane >> 4;

    f32x4 acc[4][4] = {};

    for (int k0 = 0; k0 < K; k0 += 64) {
#pragma unroll
        for (int i = 0; i < 4; ++i) {
            int chunk = i * 256 + tid;
            int row = chunk >> 3;
            int c8  = (chunk & 7) << 3;
            gld_lds16(A  + (size_t)(m0 + row) * K + k0 + c8, (char*)As + chunk * 16);
            gld_lds16(Bt + (size_t)(n0 + row) * K + k0 + c8, (char*)Bs + chunk * 16);
        }
        __syncthreads();
#pragma unroll
        for (int kk = 0; kk < 2; ++kk) {
            bf16x8 af[4], bfr[4];
#pragma unroll
            for (int f = 0; f < 4; ++f)
                af[f] = *(const bf16x8*)(As + (wrow + f * 16 + lr) * 64 + kk * 32 + lg * 8);
#pragma unroll
            for (int f = 0; f < 4; ++f)
                bfr[f] = *(const bf16x8*)(Bs + (wcol + f * 16 + lr) * 64 + kk * 32 + lg * 8);
#pragma unroll
            for (int i = 0; i < 4; ++i)
#pragma unroll
                for (int j = 0; j < 4; ++j)
                    acc[i][j] = __builtin_amdgcn_mfma_f32_16x16x32_bf16(af[i], bfr[j], acc[i][j], 0, 0, 0);
        }
        __syncthreads();
    }

    float bvals[4];
#pragma unroll
    for (int j = 0; j < 4; ++j) bvals[j] = bias[n0 + wcol + j * 16 + lr];

#pragma unroll
    for (int i = 0; i < 4; ++i) {
        const int mbase = m0 + wrow + i * 16 + lg * 4;
#pragma unroll
        for (int j = 0; j < 4; ++j) {
            const int n = n0 + wcol + j * 16 + lr;
            if (MODE == 2) {
                float* out = (float*)outp;
#pragma unroll
                for (int r = 0; r < 4; ++r)
                    out[(size_t)(mbase + r) * N + n] = acc[i][j][r] + bvals[j];
            } else if (MODE == 0) {
                unsigned short* out = (unsigned short*)outp;
                const int h = n >> 6, d = n & 63;
#pragma unroll
                for (int r = 0; r < 4; ++r) {
                    const int m = mbase + r;
                    const int b = m >> 11, t = m & 2047;
                    out[((size_t)(b * NH + h) * SEQ + t) * HD + d] = f2bf((acc[i][j][r] + bvals[j]) * oscale);
                }
            } else { // MODE 1: (B,H,D,T), pack 4 consecutive t
                unsigned short* out = (unsigned short*)outp;
                const int h = n >> 6, d = n & 63;
                const int b = mbase >> 11, t = mbase & 2047;
                union { unsigned short s[4]; uint2 v; } pk;
#pragma unroll
                for (int r = 0; r < 4; ++r) pk.s[r] = f2bf(acc[i][j][r] + bvals[j]);
                *(uint2*)(out + ((size_t)(b * NH + h) * HD + d) * SEQ + t) = pk.v;
            }
        }
    }
}

// ---------------- flash attention ----------------
// Grid (bh=64, qtile=32), qtile = 31 - blockIdx.y (longest first). 4 waves;
// wave w owns q rows [q0+16w, q0+16w+16). K/V double-buffered + XOR-swizzled.
// Softmax in log2 domain (Q pre-scaled by 0.125*log2e): P = 2^(s - m).
// Denominator accumulated by MFMA with an all-ones B operand (exact FA).
__global__ __launch_bounds__(256, 4)
void attn_k(const unsigned short* __restrict__ Qh,   // (BH, T, 64), pre-scaled
            const unsigned short* __restrict__ Kh,   // (BH, T, 64)
            const unsigned short* __restrict__ Vt,   // (BH, 64, T)
            unsigned short* __restrict__ O) {        // (B, T, H*64)
    __shared__ unsigned short Ks[2][64 * 64];
    __shared__ unsigned short Vs[2][64 * 64];   // [d][kv]
    __shared__ unsigned short Ps[4][16 * 64];   // per-wave P tile (swizzled)
    const int bh    = blockIdx.x;
    const int qtile = 31 - blockIdx.y;          // longest first
    const int q0    = qtile << 6;
    const int tid  = threadIdx.x;
    const int lane = tid & 63;
    const int w    = tid >> 6;
    const int lr   = lane & 15;
    const int lg   = lane >> 4;
    const int qw   = q0 + w * 16;               // wave's first q row
    unsigned short* Pw = Ps[w];

    bf16x8 vones;
#pragma unroll
    for (int j = 0; j < 8; ++j) vones[j] = (short)0x3F80;   // bf16 1.0

    // Q fragment in registers (rows qw+lr, d = kk*32+lg*8)
    bf16x8 qf[2];
#pragma unroll
    for (int kk = 0; kk < 2; ++kk)
        qf[kk] = *(const bf16x8*)(Qh + ((size_t)bh * SEQ + qw + lr) * HD + kk * 32 + lg * 8);

    float mrun[4];
    f32x4 oacc[4] = {};
    f32x4 osum = {};
#pragma unroll
    for (int r = 0; r < 4; ++r) mrun[r] = -3e38f;

    const int nkt = qtile + 1;   // kv tiles of 64 covering [0, q0+64)

#define STAGE(KT, B) do {                                                          \
        const int kv_ = (KT) << 6;                                                 \
        _Pragma("unroll")                                                          \
        for (int i_ = 0; i_ < 2; ++i_) {                                           \
            int c_ = i_ * 256 + tid;                                               \
            int row_ = c_ >> 3;                                                    \
            int so_ = (((c_ & 7) ^ (row_ & 7)) << 3);                              \
            gld_lds16(Kh + ((size_t)bh * SEQ + kv_ + row_) * HD + so_,             \
                      (char*)Ks[B] + c_ * 16);                                     \
            gld_lds16(Vt + ((size_t)bh * HD + row_) * SEQ + kv_ + so_,             \
                      (char*)Vs[B] + c_ * 16);                                     \
        }                                                                          \
    } while (0)

    STAGE(0, 0);
    __syncthreads();

    for (int kt = 0; kt < nkt; ++kt) {
        if (kt + 1 < nkt) STAGE(kt + 1, (kt + 1) & 1);
        const unsigned short* Kc = Ks[kt & 1];
        const unsigned short* Vc = Vs[kt & 1];
        const int kv0 = kt << 6;

        {
            // ---- QK^T (log2-domain scores: Q pre-scaled) ----
            f32x4 s[4] = {};
#pragma unroll
            for (int kk = 0; kk < 2; ++kk) {
                const int u = (((kk << 2) | lg) ^ (lr & 7)) << 3;
#pragma unroll
                for (int f = 0; f < 4; ++f) {
                    bf16x8 kb = *(const bf16x8*)(Kc + (f * 16 + lr) * 64 + u);
                    s[f] = __builtin_amdgcn_mfma_f32_16x16x32_bf16(qf[kk], kb, s[f], 0, 0, 0);
                }
            }

            // ---- causal mask (diag tile only) + row max ----
            float rmax[4];
#pragma unroll
            for (int r = 0; r < 4; ++r) rmax[r] = -3e38f;
            if (kv0 + 63 <= qw) {      // full tile: no masking, no scaling
#pragma unroll
                for (int f = 0; f < 4; ++f)
#pragma unroll
                    for (int r = 0; r < 4; ++r) rmax[r] = fmaxf(rmax[r], s[f][r]);
            } else {
#pragma unroll
                for (int f = 0; f < 4; ++f)
#pragma unroll
                    for (int r = 0; r < 4; ++r) {
                        const int q  = qw + lg * 4 + r;
                        const int kv = kv0 + f * 16 + lr;
                        float v = (kv > q) ? -3e38f : s[f][r];
                        s[f][r] = v;
                        rmax[r] = fmaxf(rmax[r], v);
                    }
            }
#pragma unroll
            for (int d = 1; d < 16; d <<= 1)
#pragma unroll
                for (int r = 0; r < 4; ++r)
                    rmax[r] = fmaxf(rmax[r], __shfl_xor(rmax[r], d));

            // ---- deferred rescale: only when the running max grows ----
            bool grow = (rmax[0] > mrun[0]) | (rmax[1] > mrun[1]) |
                        (rmax[2] > mrun[2]) | (rmax[3] > mrun[3]);
            if (__any(grow)) {
#pragma unroll
                for (int r = 0; r < 4; ++r) {
                    float mn = fmaxf(mrun[r], rmax[r]);
                    float c  = fast_exp2(mrun[r] - mn);
                    mrun[r]  = mn;
                    osum[r] *= c;
#pragma unroll
                    for (int f = 0; f < 4; ++f) oacc[f][r] *= c;
                }
            }

            // ---- P = 2^(s-m); pack pairs to bf16; write swizzled LDS ----
#pragma unroll
            for (int f = 0; f < 4; ++f)
#pragma unroll
                for (int r = 0; r < 4; ++r)
                    s[f][r] = fast_exp2(s[f][r] - mrun[r]);
#pragma unroll
            for (int f = 0; f < 4; ++f)
#pragma unroll
                for (int rp = 0; rp < 2; ++rp) {
                    unsigned pk = cvt_pk_bf16(s[f][2 * rp], s[f][2 * rp + 1]);
                    const int p0 = lg * 4 + 2 * rp;
                    const int p1 = p0 + 1;
                    Pw[p0 * 64 + ((f * 16 + lr) ^ ((p0 & 7) << 3))] = (unsigned short)pk;
                    Pw[p1 * 64 + ((f * 16 + lr) ^ ((p1 & 7) << 3))] = (unsigned short)(pk >> 16);
                }

            bf16x8 pa[2];
#pragma unroll
            for (int kk = 0; kk < 2; ++kk)
                pa[kk] = *(const bf16x8*)(Pw + lr * 64 + ((((kk << 2) | lg) ^ (lr & 7)) << 3));

            // ---- PV + denominator via all-ones MFMA ----
#pragma unroll
            for (int kk = 0; kk < 2; ++kk) {
                const int u = (((kk << 2) | lg) ^ (lr & 7)) << 3;
#pragma unroll
                for (int f = 0; f < 4; ++f) {
                    bf16x8 vb = *(const bf16x8*)(Vc + (f * 16 + lr) * 64 + u);
                    oacc[f] = __builtin_amdgcn_mfma_f32_16x16x32_bf16(pa[kk], vb, oacc[f], 0, 0, 0);
                }
                osum = __builtin_amdgcn_mfma_f32_16x16x32_bf16(pa[kk], vones, osum, 0, 0, 0);
            }
        }
        __syncthreads();
    }
#undef STAGE

    const int b = bh >> 4, h = bh & 15;
    float inv[4];
#pragma unroll
    for (int r = 0; r < 4; ++r) inv[r] = 1.0f / osum[r];
#pragma unroll
    for (int f = 0; f < 4; ++f) {
        const int d = f * 16 + lr;
#pragma unroll
        for (int r = 0; r < 4; ++r) {
            const int t = qw + lg * 4 + r;
            O[((size_t)b * SEQ + t) * CH + h * HD + d] = f2bf(oacc[f][r] * inv[r]);
        }
    }
}

extern "C" void kernel_launch(void* const* d_in, const int* in_sizes, int n_in,
                              void* d_out, int out_size, void* d_ws, size_t ws_size,
                              hipStream_t stream) {
    const float* Q  = (const float*)d_in[0];
    const float* K  = (const float*)d_in[1];
    const float* V  = (const float*)d_in[2];
    // d_in[3] = mask: always causal triu(k=1); applied analytically in attn_k
    const float* Wq = (const float*)d_in[4];
    const float* bq = (const float*)d_in[5];
    const float* Wk = (const float*)d_in[6];
    const float* bk = (const float*)d_in[7];
    const float* Wv = (const float*)d_in[8];
    const float* bv = (const float*)d_in[9];
    const float* Wo = (const float*)d_in[10];
    const float* bo = (const float*)d_in[11];
    float* out = (float*)d_out;

    const size_t SZ_ACT = (size_t)BATCH * SEQ * CH;  // 8388608
    const size_t SZ_W   = (size_t)CH * CH;           // 1048576

    char* p = (char*)d_ws;
    unsigned short* Qbf = (unsigned short*)p; p += SZ_ACT * 2;
    unsigned short* Kbf = (unsigned short*)p; p += SZ_ACT * 2;
    unsigned short* Vbf = (unsigned short*)p; p += SZ_ACT * 2;
    unsigned short* WqT = (unsigned short*)p; p += SZ_W * 2;
    unsigned short* WkT = (unsigned short*)p; p += SZ_W * 2;
    unsigned short* WvT = (unsigned short*)p; p += SZ_W * 2;
    unsigned short* WoT = (unsigned short*)p; p += SZ_W * 2;
    unsigned short* Qhb = (unsigned short*)p; p += SZ_ACT * 2;
    unsigned short* Khb = (unsigned short*)p; p += SZ_ACT * 2;
    unsigned short* Vtb = (unsigned short*)p; p += SZ_ACT * 2;
    unsigned short* Ob  = Qbf;  // Qbf is dead after the Q projection; reuse for attn output

    const int nconv = (int)SZ_ACT;
    const int cblocks = (int)(SZ_ACT / (256 * 8));
    cvt_bf16_k<<<cblocks, 256, 0, stream>>>(Q, Qbf, nconv);
    cvt_bf16_k<<<cblocks, 256, 0, stream>>>(K, Kbf, nconv);
    cvt_bf16_k<<<cblocks, 256, 0, stream>>>(V, Vbf, nconv);

    transpose_w_k<<<dim3(32, 32), 256, 0, stream>>>(Wq, WqT);
    transpose_w_k<<<dim3(32, 32), 256, 0, stream>>>(Wk, WkT);
    transpose_w_k<<<dim3(32, 32), 256, 0, stream>>>(Wv, WvT);
    transpose_w_k<<<dim3(32, 32), 256, 0, stream>>>(Wo, WoT);

    const int M = BATCH * SEQ;  // 8192
    gemm_bt<0><<<(M / 128) * (CH / 128), 256, 0, stream>>>(Qbf, WqT, bq, Qhb, M, CH, CH, QSCALE);
    gemm_bt<0><<<(M / 128) * (CH / 128), 256, 0, stream>>>(Kbf, WkT, bk, Khb, M, CH, CH, 1.0f);
    gemm_bt<1><<<(M / 128) * (CH / 128), 256, 0, stream>>>(Vbf, WvT, bv, Vtb, M, CH, CH, 1.0f);

    attn_k<<<dim3(BATCH * NH, SEQ / 64), 256, 0, stream>>>(Qhb, Khb, Vtb, Ob);

    gemm_bt<2><<<(M / 128) * (CH / 128), 256, 0, stream>>>(Ob, WoT, bo, out, M, CH, CH, 1.0f);
}